// Round 16
// baseline (49.288 us; speedup 1.0000x reference)
//
#include <hip/hip_runtime.h>

#define M_ROWS  4096
#define IN_DIM  512
#define NEURONS 1024
#define OUT_DIM 512

typedef _Float16 f16;
typedef __attribute__((ext_vector_type(8))) _Float16 f16x8;
typedef __attribute__((ext_vector_type(4))) _Float16 f16x4;
typedef __attribute__((ext_vector_type(4))) float    f32x4;

#define GLD(srcp, dstp) __builtin_amdgcn_global_load_lds( \
    (const __attribute__((address_space(1))) void*)(srcp), \
    (__attribute__((address_space(3))) void*)(dstp), 16, 0, 0)

// ===========================================================================
// prep: (verbatim R11/R15)
// ===========================================================================
__global__ __launch_bounds__(256) void prep(
    const float* __restrict__ x,  f16* __restrict__ xh,
    const float* __restrict__ W1, f16* __restrict__ W1t,
    const float* __restrict__ W2, f16* __restrict__ W2t,
    const float* __restrict__ coeff, const float* __restrict__ spb,
    f16* __restrict__ cpH)
{
    __shared__ float S[32][33];
    const int b = blockIdx.x, t = threadIdx.x;
    if (b < 1024) {
        int i = b * 256 + t;
        const float4* p = (const float4*)x;
        float4 a = p[i * 2], c = p[i * 2 + 1];
        f16x8 o = { (f16)a.x, (f16)a.y, (f16)a.z, (f16)a.w,
                    (f16)c.x, (f16)c.y, (f16)c.z, (f16)c.w };
        *(f16x8*)(xh + (size_t)i * 8) = o;
        return;
    }
    if (b < 1536) {                       // W1 transpose -> f16
        const int tile = b - 1024;
        const int tx = tile & 31, ty = tile >> 5;
        const int tr = t >> 3, tc = (t & 7) * 4;
        float4 v = *(const float4*)&W1[(size_t)(ty * 32 + tr) * NEURONS + tx * 32 + tc];
        S[tr][tc + 0] = v.x; S[tr][tc + 1] = v.y;
        S[tr][tc + 2] = v.z; S[tr][tc + 3] = v.w;
        __syncthreads();
        f16x4 o = {(f16)S[tc + 0][tr], (f16)S[tc + 1][tr],
                   (f16)S[tc + 2][tr], (f16)S[tc + 3][tr]};
        *(f16x4*)&W1t[(size_t)(tx * 32 + tr) * IN_DIM + ty * 32 + tc] = o;
        return;
    }
    if (b < 2048) {                       // W2 transpose -> f16, swizzled
        const int tile = b - 1536;
        const int nt = tile & 15, kt2 = tile >> 4;
        const int tr = t >> 3, tc = (t & 7) * 4;
        float4 v = *(const float4*)&W2[(size_t)(kt2 * 32 + tr) * OUT_DIM + nt * 32 + tc];
        S[tr][tc + 0] = v.x; S[tr][tc + 1] = v.y;
        S[tr][tc + 2] = v.z; S[tr][tc + 3] = v.w;
        __syncthreads();
        const int n = nt * 32 + tr;
        f16x4 o = {(f16)S[tc + 0][tr], (f16)S[tc + 1][tr],
                   (f16)S[tc + 2][tr], (f16)S[tc + 3][tr]};
        const int kbyte = ((kt2 * 32 + tc) * 2) ^ ((n & 7) << 4);
        *(f16x4*)((char*)W2t + (size_t)n * 2048 + kbyte) = o;
        return;
    }
    {                                     // cpH table (f16)
        const int tid = (b - 2048) * 256 + t;
        if (tid < NEURONS * 15) {
            const int n = tid / 15, ii = tid % 15;
            const float s = spb[n];
            f16x4 c;
            c[0] = (f16)(coeff[n * 18 + ii]     + s);
            c[1] = (f16)(coeff[n * 18 + ii + 1] + s);
            c[2] = (f16)(coeff[n * 18 + ii + 2] + s);
            c[3] = (f16)(coeff[n * 18 + ii + 3] + s);
            *(f16x4*)&cpH[(size_t)tid * 4] = c;
        }
    }
}

// ===========================================================================
// gemm1: (verbatim R11/R15)
// ===========================================================================
__global__ __launch_bounds__(256) void k_gemm1(
    const f16* __restrict__ A, const f16* __restrict__ Bt,
    const float* __restrict__ b1, f16* __restrict__ h,
    float* __restrict__ pmin, float* __restrict__ pmax)
{
    __shared__ f16 lds[2][(128 + 64) * 64];   // 48 KB

    const int t    = threadIdx.x;
    const int lane = t & 63, l15 = lane & 15, lhi = lane >> 4;
    const int wid  = t >> 6;
    const int wm   = wid >> 1, wn = wid & 1;

    const int flat = blockIdx.y * gridDim.x + blockIdx.x;   // 512 blocks
    const int swz  = (flat & 7) * 64 + (flat >> 3);
    const int m0   = (swz >> 4) * 128;
    const int n0   = (swz & 15) * 64;

    auto stage = [&](int buf, int kt) {
        f16* base = &lds[buf][0];
#pragma unroll
        for (int j = 0; j < 4; ++j) {
            int c = wid * 4 + j;
            GLD(A + (size_t)(m0 + c * 8 + (lane >> 3)) * IN_DIM + kt + (lane & 7) * 8,
                base + c * 512);
        }
#pragma unroll
        for (int j = 0; j < 2; ++j) {
            int c = wid * 2 + j;
            GLD(Bt + (size_t)(n0 + c * 8 + (lane >> 3)) * IN_DIM + kt + (lane & 7) * 8,
                base + 8192 + c * 512);
        }
    };

    f32x4 acc[4][2];
#pragma unroll
    for (int i = 0; i < 4; ++i)
#pragma unroll
        for (int j = 0; j < 2; ++j) acc[i][j] = (f32x4)0.f;

    stage(0, 0);
    __syncthreads();

    int cur = 0;
    for (int tt = 0; tt < 8; ++tt) {                     // K = 512
        if (tt < 7) stage(cur ^ 1, (tt + 1) * 64);
        const f16* L = &lds[cur][0];
#pragma unroll
        for (int ks = 0; ks < 2; ++ks) {
            f16x8 bfr[2];
#pragma unroll
            for (int nj = 0; nj < 2; ++nj)
                bfr[nj] = *(const f16x8*)
                    &L[8192 + (wn * 32 + nj * 16 + l15) * 64 + ks * 32 + lhi * 8];
#pragma unroll
            for (int mi = 0; mi < 4; ++mi) {
                f16x8 afr = *(const f16x8*)
                    &L[(wm * 64 + mi * 16 + l15) * 64 + ks * 32 + lhi * 8];
#pragma unroll
                for (int nj = 0; nj < 2; ++nj)
                    acc[mi][nj] = __builtin_amdgcn_mfma_f32_16x16x32_f16(
                        afr, bfr[nj], acc[mi][nj], 0, 0, 0);
            }
        }
        __syncthreads();
        cur ^= 1;
    }

    const int nb2 = (n0 >> 6) * 2 + wn;                  // 0..31
#pragma unroll
    for (int mi = 0; mi < 4; ++mi) {
        const int row0 = m0 + wm * 64 + mi * 16 + lhi * 4;
        float vmn[4], vmx[4];
#pragma unroll
        for (int nj = 0; nj < 2; ++nj) {
            const int col = n0 + wn * 32 + nj * 16 + l15;
            const float bv = b1[col];
#pragma unroll
            for (int j = 0; j < 4; ++j) {
                f16 hv = (f16)(acc[mi][nj][j] + bv);
                h[(size_t)(row0 + j) * NEURONS + col] = hv;
                float vr = (float)hv;
                if (nj == 0) { vmn[j] = vr; vmx[j] = vr; }
                else { vmn[j] = fminf(vmn[j], vr); vmx[j] = fmaxf(vmx[j], vr); }
            }
        }
#pragma unroll
        for (int j = 0; j < 4; ++j) {
#pragma unroll
            for (int d = 1; d < 16; d <<= 1) {
                vmn[j] = fminf(vmn[j], __shfl_xor(vmn[j], d));
                vmx[j] = fmaxf(vmx[j], __shfl_xor(vmx[j], d));
            }
        }
        if (l15 == 0) {
#pragma unroll
            for (int j = 0; j < 4; ++j) {
                pmin[(size_t)nb2 * M_ROWS + row0 + j] = vmn[j];
                pmax[(size_t)nb2 * M_ROWS + row0 + j] = vmx[j];
            }
        }
    }
}

// ===========================================================================
// sp_gemm2 v6: v3 geometry (BM=32 BN=128 BK=64, 512 blocks, dbuf everything)
// with T4 sync structure: ALL loop loads are global_load_lds (B=4, cp=2,
// h-slice=1 per wave per step); raw s_barrier + counted s_waitcnt vmcnt(N).
// Ledger: step s issues 7 DMAs then vmcnt(7) -> drains exactly step s-1's 7.
// Every load gets one full step in flight; barrier never drains vmem.
// ===========================================================================
__global__ __launch_bounds__(256) void sp_gemm2(
    const f16* __restrict__ h, const float* __restrict__ pmin,
    const float* __restrict__ pmax, const f16* __restrict__ cpH,
    const f16* __restrict__ W2t, const float* __restrict__ b2,
    float* __restrict__ out)
{
    __shared__ __align__(16) f16 Bb[2][128 * 64];        // 32 KB
    __shared__ __align__(16) f16 Aa[2][32 * 72];         // 9 KB (padded)
    __shared__ __align__(16) f16 cpS[2][4096];           // 16 KB
    __shared__ __align__(16) f16 hS[2][32 * 64];         // 8 KB
    __shared__ float mnS[32], invS[32];

    const int t    = threadIdx.x;
    const int lane = t & 63, l15 = lane & 15, lhi = lane >> 4;
    const int wid  = t >> 6;
    const int wm   = wid & 1, wn = wid >> 1;

    const int flat = blockIdx.x;                         // 512 blocks
    const int swz  = (flat & 7) * 64 + (flat >> 3);
    const int m0   = (swz & 127) * 32;
    const int n0   = (swz >> 7) * 128;

    auto stageB = [&](int s) {                           // 4 DMA/wave
        char* base = (char*)&Bb[s & 1][0];
#pragma unroll
        for (int j = 0; j < 4; ++j) {
            const int c = wid * 4 + j;
            GLD((const char*)W2t + (size_t)(n0 + c * 8 + (lane >> 3)) * 2048
                    + s * 128 + (lane & 7) * 16,
                base + c * 1024);
        }
    };
    auto stageCp = [&](int s) {                          // 2 DMA/wave
        const char* src = (const char*)cpH + (size_t)s * 7680 + (wid * 64 + lane) * 16;
        char* base = (char*)&cpS[s & 1][0];
        GLD(src,        base + wid * 1024);
        GLD(src + 4096, base + 4096 + wid * 1024);
    };
    auto stageH = [&](int s) {                           // 1 DMA/wave
        GLD(h + (size_t)(m0 + wid * 8 + (lane >> 3)) * NEURONS + s * 64 + (lane & 7) * 8,
            (char*)&hS[s & 1][0] + wid * 1024);
    };

    const int sr_ = t >> 3;                              // spline row 0..31
    const int sk8 = (t & 7) * 8;                         // k-offset 0..56
    auto splineA = [&](int s) {
        const float mn = mnS[sr_], inv = invS[sr_];
        const f16* cps = &cpS[s & 1][0];
        f16x8 hv = *(const f16x8*)&hS[s & 1][sr_ * 64 + sk8];
        f16x8 o;
#pragma unroll
        for (int e = 0; e < 8; ++e) {
            const float u   = ((float)hv[e] - mn) * inv;
            const float t15 = u * 15.0f;
            int ii = (int)t15;
            ii = ii < 0 ? 0 : (ii > 14 ? 14 : ii);
            const float tl  = t15 - (float)ii;
            const float t2  = tl * tl, t3 = t2 * tl;
            const float omt = 1.0f - tl;
            const float b0  = omt * omt * omt * (1.0f / 6.0f);
            const float b3v = t3 * (1.0f / 6.0f);
            const float b1v = (4.0f / 6.0f) - t2 + 0.5f * t3;
            const float b2v = (1.0f / 6.0f) + 0.5f * (tl + t2 - t3);
            const f16x4 c   = *(const f16x4*)&cps[((sk8 + e) * 15 + ii) * 4];
            o[e] = (f16)((float)c[0] * b0 + (float)c[1] * b1v
                       + (float)c[2] * b2v + (float)c[3] * b3v);
        }
        *(f16x8*)&Aa[s & 1][sr_ * 72 + sk8] = o;
    };

    // ---- prologue: stage {B0, cp0, cp1, h0, h1}; minmax; full drain -------
    stageB(0); stageCp(0); stageCp(1); stageH(0); stageH(1);
    if (t < 32) {
        const int row = m0 + t;
        float a = pmin[row], b = pmax[row];
#pragma unroll
        for (int p = 1; p < 32; ++p) {
            a = fminf(a, pmin[(size_t)p * M_ROWS + row]);
            b = fmaxf(b, pmax[(size_t)p * M_ROWS + row]);
        }
        mnS[t] = a;
        invS[t] = 1.0f / (b - a + 1e-8f);
    }
    __syncthreads();          // vmcnt(0): all prologue DMAs resident; mnS visible
    splineA(0);
    asm volatile("s_waitcnt lgkmcnt(0)" ::: "memory");
    __builtin_amdgcn_s_barrier();                        // Aa[0] visible
    __builtin_amdgcn_sched_barrier(0);

    f32x4 acc[4];
#pragma unroll
    for (int j = 0; j < 4; ++j) acc[j] = (f32x4)0.f;

    for (int s = 0; s < 16; ++s) {                       // K = 1024
        // issue this step's DMAs (targets: (s+1)/(s+2) buffers, all free)
        if (s + 1 < 16) stageB(s + 1);
        if (s + 2 < 16) { stageCp(s + 2); stageH(s + 2); }
        // counted drain: leave exactly this step's issues in flight
        if (s + 2 < 16)      { asm volatile("s_waitcnt vmcnt(7)" ::: "memory"); }
        else if (s + 1 < 16) { asm volatile("s_waitcnt vmcnt(4)" ::: "memory"); }
        else                 { asm volatile("s_waitcnt vmcnt(0)" ::: "memory"); }
        __builtin_amdgcn_sched_barrier(0);
        if (s + 1 < 16) splineA(s + 1);                  // cpS/hS[(s+1)&1] resident
        // ---- MFMA on buffers s ------------------------------------------
        {
            const char* B_ = (const char*)&Bb[s & 1][0];
            const f16*  A_ = &Aa[s & 1][0];
#pragma unroll
            for (int ks = 0; ks < 2; ++ks) {
                f16x8 afr = *(const f16x8*)&A_[(wm * 16 + l15) * 72 + ks * 32 + lhi * 8];
#pragma unroll
                for (int nj = 0; nj < 4; ++nj) {
                    const int cl = wn * 64 + nj * 16 + l15;
                    const int kb = (ks * 64 + lhi * 16) ^ ((cl & 7) << 4);
                    f16x8 bfr = *(const f16x8*)(B_ + (size_t)cl * 128 + kb);
                    acc[nj] = __builtin_amdgcn_mfma_f32_16x16x32_f16(afr, bfr, acc[nj], 0, 0, 0);
                }
            }
        }
        asm volatile("s_waitcnt lgkmcnt(0)" ::: "memory");  // Aa writes visible
        __builtin_amdgcn_s_barrier();                       // no vmem drain here
        __builtin_amdgcn_sched_barrier(0);
    }

    // epilogue: col = l15, row = lhi*4 + j
    const int row0 = m0 + wm * 16 + lhi * 4;
#pragma unroll
    for (int nj = 0; nj < 4; ++nj) {
        const int col = n0 + wn * 64 + nj * 16 + l15;
        const float bv = b2[col];
#pragma unroll
        for (int j = 0; j < 4; ++j)
            out[(size_t)(row0 + j) * OUT_DIM + col] =
                fmaxf(acc[nj][j] + bv, 0.0f);
    }
}

// ===========================================================================
extern "C" void kernel_launch(void* const* d_in, const int* in_sizes, int n_in,
                              void* d_out, int out_size, void* d_ws, size_t ws_size,
                              hipStream_t stream)
{
    const float* x     = (const float*)d_in[0];
    const float* W1    = (const float*)d_in[1];
    const float* b1    = (const float*)d_in[2];
    const float* coeff = (const float*)d_in[3];
    const float* spb   = (const float*)d_in[4];
    const float* W2    = (const float*)d_in[5];
    const float* b2    = (const float*)d_in[6];
    float* out = (float*)d_out;

    char* ws = (char*)d_ws;
    f16*   h    = (f16*)ws;                                   //  8 MB [4096][1024]
    f16*   xh   = (f16*)(ws + ( 8u << 20));                   //  4 MB [4096][512]
    f16*   W1t  = (f16*)(ws + (12u << 20));                   //  1 MB [1024][512]
    f16*   W2t  = (f16*)(ws + (13u << 20));                   //  1 MB [512][1024] swz
    float* pmin = (float*)(ws + (14u << 20));                 // 512 KB [32][4096]
    float* pmax = (float*)(ws + (14u << 20) + (512u << 10));  // 512 KB
    f16*   cpH  = (f16*)(ws + (15u << 20));                   // 120 KB [1024][15][4]

    prep<<<dim3(2108), 256, 0, stream>>>(x, xh, W1, W1t, W2, W2t, coeff, spb, cpH);

    k_gemm1<<<dim3(16, 32), 256, 0, stream>>>(xh, W1t, b1, h, pmin, pmax);

    sp_gemm2<<<dim3(512), 256, 0, stream>>>(h, pmin, pmax, cpH, W2t, b2, out);
}

// Round 17
// 44.868 us; speedup vs baseline: 1.0985x; 1.0985x over previous
//
#include <hip/hip_runtime.h>

#define M_ROWS  4096
#define IN_DIM  512
#define NEURONS 1024
#define OUT_DIM 512

typedef _Float16 f16;
typedef __attribute__((ext_vector_type(8))) _Float16 f16x8;
typedef __attribute__((ext_vector_type(4))) _Float16 f16x4;
typedef __attribute__((ext_vector_type(4))) float    f32x4;

// ===========================================================================
// prep:
//  [0,1024)    x f32 -> xh f16
//  [1024,1536) W1 -> W1t [1024][512] f16
//  [1536,2048) W2 -> W2t [512][1024] f16, pre-XOR-swizzled kbyte ^= (n&7)<<4
//  [2048,2108) qH[n][ii][4] f16 = POWER-BASIS cubic coeffs of the spline
//              segment (Horner form); spb folds into q0 (partition of unity).
// ===========================================================================
__global__ __launch_bounds__(256) void prep(
    const float* __restrict__ x,  f16* __restrict__ xh,
    const float* __restrict__ W1, f16* __restrict__ W1t,
    const float* __restrict__ W2, f16* __restrict__ W2t,
    const float* __restrict__ coeff, const float* __restrict__ spb,
    f16* __restrict__ qH)
{
    __shared__ float S[32][33];
    const int b = blockIdx.x, t = threadIdx.x;
    if (b < 1024) {
        int i = b * 256 + t;
        const float4* p = (const float4*)x;
        float4 a = p[i * 2], c = p[i * 2 + 1];
        f16x8 o = { (f16)a.x, (f16)a.y, (f16)a.z, (f16)a.w,
                    (f16)c.x, (f16)c.y, (f16)c.z, (f16)c.w };
        *(f16x8*)(xh + (size_t)i * 8) = o;
        return;
    }
    if (b < 1536) {                       // W1 transpose -> f16
        const int tile = b - 1024;
        const int tx = tile & 31, ty = tile >> 5;
        const int tr = t >> 3, tc = (t & 7) * 4;
        float4 v = *(const float4*)&W1[(size_t)(ty * 32 + tr) * NEURONS + tx * 32 + tc];
        S[tr][tc + 0] = v.x; S[tr][tc + 1] = v.y;
        S[tr][tc + 2] = v.z; S[tr][tc + 3] = v.w;
        __syncthreads();
        f16x4 o = {(f16)S[tc + 0][tr], (f16)S[tc + 1][tr],
                   (f16)S[tc + 2][tr], (f16)S[tc + 3][tr]};
        *(f16x4*)&W1t[(size_t)(tx * 32 + tr) * IN_DIM + ty * 32 + tc] = o;
        return;
    }
    if (b < 2048) {                       // W2 transpose -> f16, swizzled
        const int tile = b - 1536;
        const int nt = tile & 15, kt2 = tile >> 4;
        const int tr = t >> 3, tc = (t & 7) * 4;
        float4 v = *(const float4*)&W2[(size_t)(kt2 * 32 + tr) * OUT_DIM + nt * 32 + tc];
        S[tr][tc + 0] = v.x; S[tr][tc + 1] = v.y;
        S[tr][tc + 2] = v.z; S[tr][tc + 3] = v.w;
        __syncthreads();
        const int n = nt * 32 + tr;
        f16x4 o = {(f16)S[tc + 0][tr], (f16)S[tc + 1][tr],
                   (f16)S[tc + 2][tr], (f16)S[tc + 3][tr]};
        const int kbyte = ((kt2 * 32 + tc) * 2) ^ ((n & 7) << 4);
        *(f16x4*)((char*)W2t + (size_t)n * 2048 + kbyte) = o;
        return;
    }
    {                                     // qH table (f16 power-basis coeffs)
        const int tid = (b - 2048) * 256 + t;
        if (tid < NEURONS * 15) {
            const int n = tid / 15, ii = tid % 15;
            const float s = spb[n];
            const float c0 = coeff[n * 18 + ii]     + s;
            const float c1 = coeff[n * 18 + ii + 1] + s;
            const float c2 = coeff[n * 18 + ii + 2] + s;
            const float c3 = coeff[n * 18 + ii + 3] + s;
            f16x4 q;
            q[0] = (f16)((c0 + 4.0f * c1 + c2) * (1.0f / 6.0f));
            q[1] = (f16)((c2 - c0) * 0.5f);
            q[2] = (f16)((c0 - 2.0f * c1 + c2) * 0.5f);
            q[3] = (f16)((c3 - c0 + 3.0f * (c1 - c2)) * (1.0f / 6.0f));
            *(f16x4*)&qH[(size_t)tid * 4] = q;
        }
    }
}

// ===========================================================================
// gemm1: (verbatim R11) h(f16) = x @ W1 + b1, BM=128 BN=64 BK=64,
// global_load_lds(16B), dbuf, 1 barrier/step; 32 min/max partials per row.
// ===========================================================================
__global__ __launch_bounds__(256) void k_gemm1(
    const f16* __restrict__ A, const f16* __restrict__ Bt,
    const float* __restrict__ b1, f16* __restrict__ h,
    float* __restrict__ pmin, float* __restrict__ pmax)
{
    __shared__ f16 lds[2][(128 + 64) * 64];   // 48 KB

    const int t    = threadIdx.x;
    const int lane = t & 63, l15 = lane & 15, lhi = lane >> 4;
    const int wid  = t >> 6;
    const int wm   = wid >> 1, wn = wid & 1;

    const int flat = blockIdx.y * gridDim.x + blockIdx.x;   // 512 blocks
    const int swz  = (flat & 7) * 64 + (flat >> 3);
    const int m0   = (swz >> 4) * 128;
    const int n0   = (swz & 15) * 64;

    auto stage = [&](int buf, int kt) {
        f16* base = &lds[buf][0];
#pragma unroll
        for (int j = 0; j < 4; ++j) {
            int c = wid * 4 + j;
            const f16* g = A + (size_t)(m0 + c * 8 + (lane >> 3)) * IN_DIM + kt + (lane & 7) * 8;
            __builtin_amdgcn_global_load_lds(
                (const __attribute__((address_space(1))) void*)g,
                (__attribute__((address_space(3))) void*)(base + c * 512), 16, 0, 0);
        }
#pragma unroll
        for (int j = 0; j < 2; ++j) {
            int c = wid * 2 + j;
            const f16* g = Bt + (size_t)(n0 + c * 8 + (lane >> 3)) * IN_DIM + kt + (lane & 7) * 8;
            __builtin_amdgcn_global_load_lds(
                (const __attribute__((address_space(1))) void*)g,
                (__attribute__((address_space(3))) void*)(base + 8192 + c * 512), 16, 0, 0);
        }
    };

    f32x4 acc[4][2];
#pragma unroll
    for (int i = 0; i < 4; ++i)
#pragma unroll
        for (int j = 0; j < 2; ++j) acc[i][j] = (f32x4)0.f;

    stage(0, 0);
    __syncthreads();

    int cur = 0;
    for (int tt = 0; tt < 8; ++tt) {                     // K = 512
        if (tt < 7) stage(cur ^ 1, (tt + 1) * 64);
        const f16* L = &lds[cur][0];
#pragma unroll
        for (int ks = 0; ks < 2; ++ks) {
            f16x8 bfr[2];
#pragma unroll
            for (int nj = 0; nj < 2; ++nj)
                bfr[nj] = *(const f16x8*)
                    &L[8192 + (wn * 32 + nj * 16 + l15) * 64 + ks * 32 + lhi * 8];
#pragma unroll
            for (int mi = 0; mi < 4; ++mi) {
                f16x8 afr = *(const f16x8*)
                    &L[(wm * 64 + mi * 16 + l15) * 64 + ks * 32 + lhi * 8];
#pragma unroll
                for (int nj = 0; nj < 2; ++nj)
                    acc[mi][nj] = __builtin_amdgcn_mfma_f32_16x16x32_f16(
                        afr, bfr[nj], acc[mi][nj], 0, 0, 0);
            }
        }
        __syncthreads();
        cur ^= 1;
    }

    const int nb2 = (n0 >> 6) * 2 + wn;                  // 0..31
#pragma unroll
    for (int mi = 0; mi < 4; ++mi) {
        const int row0 = m0 + wm * 64 + mi * 16 + lhi * 4;
        float vmn[4], vmx[4];
#pragma unroll
        for (int nj = 0; nj < 2; ++nj) {
            const int col = n0 + wn * 32 + nj * 16 + l15;
            const float bv = b1[col];
#pragma unroll
            for (int j = 0; j < 4; ++j) {
                f16 hv = (f16)(acc[mi][nj][j] + bv);
                h[(size_t)(row0 + j) * NEURONS + col] = hv;
                float vr = (float)hv;
                if (nj == 0) { vmn[j] = vr; vmx[j] = vr; }
                else { vmn[j] = fminf(vmn[j], vr); vmx[j] = fmaxf(vmx[j], vr); }
            }
        }
#pragma unroll
        for (int j = 0; j < 4; ++j) {
#pragma unroll
            for (int d = 1; d < 16; d <<= 1) {
                vmn[j] = fminf(vmn[j], __shfl_xor(vmn[j], d));
                vmx[j] = fmaxf(vmx[j], __shfl_xor(vmx[j], d));
            }
        }
        if (l15 == 0) {
#pragma unroll
            for (int j = 0; j < 4; ++j) {
                pmin[(size_t)nb2 * M_ROWS + row0 + j] = vmn[j];
                pmax[(size_t)nb2 * M_ROWS + row0 + j] = vmx[j];
            }
        }
    }
}

// ===========================================================================
// sp_gemm2 v7: R11's v3 (best measured, 48.0) with the spline eval replaced
// by power-basis Horner: t15 = fma(h, s15, o15); clamp; 1 gather (qH slice
// in LDS); 3 FMA. ~14 VALU ops/elem vs ~26. Structure otherwise verbatim.
// BM=32, BN=128, BK=64, 512 blocks (2/CU), all buffers double.
// ===========================================================================
__global__ __launch_bounds__(256) void sp_gemm2(
    const f16* __restrict__ h, const float* __restrict__ pmin,
    const float* __restrict__ pmax, const f16* __restrict__ qH,
    const f16* __restrict__ W2t, const float* __restrict__ b2,
    float* __restrict__ out)
{
    __shared__ __align__(16) f16 Bb[2][128 * 64];        // 32 KB
    __shared__ __align__(16) f16 Aa[2][32 * 72];         // 9 KB (padded)
    __shared__ __align__(16) f16 cpS[2][4096];           // 16 KB
    __shared__ float sS[32], oS[32];

    const int t    = threadIdx.x;
    const int lane = t & 63, l15 = lane & 15, lhi = lane >> 4;
    const int wid  = t >> 6;
    const int wm   = wid & 1, wn = wid >> 1;

    const int flat = blockIdx.x;
    const int swz  = (flat & 7) * 64 + (flat >> 3);
    const int m0   = (swz & 127) * 32;
    const int n0   = (swz >> 7) * 128;

    auto stageB = [&](int s) {
        f16* base = &Bb[s & 1][0];
#pragma unroll
        for (int j = 0; j < 4; ++j) {
            const int c = wid * 4 + j;                   // 16 chunks of 8 rows
            const char* src = (const char*)W2t + (size_t)(n0 + c * 8 + (lane >> 3)) * 2048
                              + s * 128 + (lane & 7) * 16;
            __builtin_amdgcn_global_load_lds(
                (const __attribute__((address_space(1))) void*)src,
                (__attribute__((address_space(3))) void*)((char*)base + c * 1024),
                16, 0, 0);
        }
    };
    auto stageCp = [&](int s) {
        const char* src = (const char*)qH + (size_t)s * 7680 + (wid * 64 + lane) * 16;
        char* base = (char*)&cpS[s & 1][0];
        __builtin_amdgcn_global_load_lds(
            (const __attribute__((address_space(1))) void*)src,
            (__attribute__((address_space(3))) void*)(base + wid * 1024), 16, 0, 0);
        __builtin_amdgcn_global_load_lds(
            (const __attribute__((address_space(1))) void*)(src + 4096),
            (__attribute__((address_space(3))) void*)(base + 4096 + wid * 1024), 16, 0, 0);
    };

    const int sr_ = t >> 3;                              // spline row 0..31
    const int sk8 = (t & 7) * 8;                         // k-offset 0..56
    auto splineA = [&](int s) {
        const float s15 = sS[sr_], o15 = oS[sr_];
        const f16* cps = &cpS[s & 1][0];
        f16x8 hv = *(const f16x8*)&h[(size_t)(m0 + sr_) * NEURONS + s * 64 + sk8];
        f16x8 o;
#pragma unroll
        for (int e = 0; e < 8; ++e) {
            const float t15 = fmaf((float)hv[e], s15, o15);
            float fi = floorf(t15);
            fi = fminf(fmaxf(fi, 0.0f), 14.0f);          // med3 clamp
            const int   ii = (int)fi;
            const float tl = t15 - fi;
            const f16x4 q  = *(const f16x4*)&cps[((sk8 + e) * 15 + ii) * 4];
            const float r  = fmaf(fmaf(fmaf((float)q[3], tl, (float)q[2]),
                                       tl, (float)q[1]),
                                  tl, (float)q[0]);
            o[e] = (f16)r;
        }
        *(f16x8*)&Aa[s & 1][sr_ * 72 + sk8] = o;
    };

    // ---- prologue --------------------------------------------------------
    stageCp(0); stageCp(1); stageB(0);
    if (t < 32) {
        const int row = m0 + t;
        float a = pmin[row], b = pmax[row];
#pragma unroll
        for (int p = 1; p < 32; ++p) {
            a = fminf(a, pmin[(size_t)p * M_ROWS + row]);
            b = fmaxf(b, pmax[(size_t)p * M_ROWS + row]);
        }
        const float s15 = 15.0f / (b - a + 1e-8f);
        sS[t] = s15;
        oS[t] = -a * s15;
    }
    __syncthreads();          // DMAs drained; sS/oS visible
    splineA(0);
    __syncthreads();          // Aa[0] visible

    f32x4 acc[4];
#pragma unroll
    for (int j = 0; j < 4; ++j) acc[j] = (f32x4)0.f;

    for (int s = 0; s < 16; ++s) {                       // K = 1024
        if (s + 1 < 16) {
            stageB(s + 1);
            if (s + 2 < 16) stageCp(s + 2);
            splineA(s + 1);                              // cpS[(s+1)&1] resident
        }
        const char* B_ = (const char*)&Bb[s & 1][0];
        const f16*  A_ = &Aa[s & 1][0];
#pragma unroll
        for (int ks = 0; ks < 2; ++ks) {
            f16x8 afr = *(const f16x8*)&A_[(wm * 16 + l15) * 72 + ks * 32 + lhi * 8];
#pragma unroll
            for (int nj = 0; nj < 4; ++nj) {
                const int cl = wn * 64 + nj * 16 + l15;
                const int kb = (ks * 64 + lhi * 16) ^ ((cl & 7) << 4);
                f16x8 bfr = *(const f16x8*)(B_ + (size_t)cl * 128 + kb);
                acc[nj] = __builtin_amdgcn_mfma_f32_16x16x32_f16(afr, bfr, acc[nj], 0, 0, 0);
            }
        }
        __syncthreads();
    }

    // epilogue: col = l15, row = lhi*4 + j
    const int row0 = m0 + wm * 16 + lhi * 4;
#pragma unroll
    for (int nj = 0; nj < 4; ++nj) {
        const int col = n0 + wn * 64 + nj * 16 + l15;
        const float bv = b2[col];
#pragma unroll
        for (int j = 0; j < 4; ++j)
            out[(size_t)(row0 + j) * OUT_DIM + col] =
                fmaxf(acc[nj][j] + bv, 0.0f);
    }
}

// ===========================================================================
extern "C" void kernel_launch(void* const* d_in, const int* in_sizes, int n_in,
                              void* d_out, int out_size, void* d_ws, size_t ws_size,
                              hipStream_t stream)
{
    const float* x     = (const float*)d_in[0];
    const float* W1    = (const float*)d_in[1];
    const float* b1    = (const float*)d_in[2];
    const float* coeff = (const float*)d_in[3];
    const float* spb   = (const float*)d_in[4];
    const float* W2    = (const float*)d_in[5];
    const float* b2    = (const float*)d_in[6];
    float* out = (float*)d_out;

    char* ws = (char*)d_ws;
    f16*   h    = (f16*)ws;                                   //  8 MB [4096][1024]
    f16*   xh   = (f16*)(ws + ( 8u << 20));                   //  4 MB [4096][512]
    f16*   W1t  = (f16*)(ws + (12u << 20));                   //  1 MB [1024][512]
    f16*   W2t  = (f16*)(ws + (13u << 20));                   //  1 MB [512][1024] swz
    float* pmin = (float*)(ws + (14u << 20));                 // 512 KB [32][4096]
    float* pmax = (float*)(ws + (14u << 20) + (512u << 10));  // 512 KB
    f16*   qH   = (f16*)(ws + (15u << 20));                   // 120 KB [1024][15][4]

    prep<<<dim3(2108), 256, 0, stream>>>(x, xh, W1, W1t, W2, W2t, coeff, spb, qH);

    k_gemm1<<<dim3(16, 32), 256, 0, stream>>>(xh, W1t, b1, h, pmin, pmax);

    sp_gemm2<<<dim3(512), 256, 0, stream>>>(h, pmin, pmax, qH, W2t, b2, out);
}